// Round 1
// baseline (59.979 us; speedup 1.0000x reference)
//
#include <hip/hip_runtime.h>
#include <float.h>

#define OPH 7
#define OPW 7
#define NC 64
#define NH 50
#define NW 50

__global__ void __launch_bounds__(256)
roi_pool_kernel(const float* __restrict__ x,
                const int* __restrict__ rois,
                float* __restrict__ out,
                int total) {
    int idx = blockIdx.x * blockDim.x + threadIdx.x;
    if (idx >= total) return;

    int pw = idx % OPW;
    int ph = (idx / OPW) % OPH;
    int c  = (idx / (OPW * OPH)) % NC;
    int m  = idx / (OPW * OPH * NC);

    const int* r = rois + m * 5;
    int b  = r[0];
    // 0.0625 = 2^-4 exact in fp32; coords <= 799 so product is exact; trunc == floor
    int x0 = (int)((float)r[1] * 0.0625f);
    int y0 = (int)((float)r[2] * 0.0625f);
    int x1 = (int)((float)r[3] * 0.0625f);
    int y1 = (int)((float)r[4] * 0.0625f);
    int hs = y1 - y0 + 1;
    int ws = x1 - x0 + 1;

    // adaptive_max_pool2d bin: [lo, hi) within crop, offset by crop origin
    int ys = y0 + (ph * hs) / OPH;
    int ye = y0 + ((ph + 1) * hs + OPH - 1) / OPH;
    int xs = x0 + (pw * ws) / OPW;
    int xe = x0 + ((pw + 1) * ws + OPW - 1) / OPW;

    const float* xp = x + ((size_t)b * NC + c) * (NH * NW);
    float mx = -FLT_MAX;
    for (int yy = ys; yy < ye; ++yy) {
        const float* row = xp + yy * NW;
        for (int xx = xs; xx < xe; ++xx)
            mx = fmaxf(mx, row[xx]);
    }
    out[idx] = mx;
}

extern "C" void kernel_launch(void* const* d_in, const int* in_sizes, int n_in,
                              void* d_out, int out_size, void* d_ws, size_t ws_size,
                              hipStream_t stream) {
    const float* x    = (const float*)d_in[0];
    const int*   rois = (const int*)d_in[1];
    float*       out  = (float*)d_out;

    int total = out_size;          // 256 * 64 * 7 * 7 = 802816
    int block = 256;
    int grid  = (total + block - 1) / block;
    roi_pool_kernel<<<grid, block, 0, stream>>>(x, rois, out, total);
}